// Round 2
// baseline (6507.939 us; speedup 1.0000x reference)
//
#include <hip/hip_runtime.h>
#include <hip/hip_bf16.h>
#include <cstdint>

#define NFEAT 272
#define HID 512

// ---------------- Edge kernel: radial basis + scatter moments ----------------
__global__ __launch_bounds__(256) void edge_kernel(
    const float* __restrict__ R, const int* __restrict__ idx,
    const float* __restrict__ centers, const float* __restrict__ width,
    float* __restrict__ M0M1, int nEdges)
{
    int e = blockIdx.x * 256 + threadIdx.x;
    if (e >= nEdges) return;
    int i = idx[e];
    int j = idx[nEdges + e];
    float rix = R[3*(size_t)i], riy = R[3*(size_t)i+1], riz = R[3*(size_t)i+2];
    float rjx = R[3*(size_t)j], rjy = R[3*(size_t)j+1], rjz = R[3*(size_t)j+2];
    float dx = rjx - rix, dy = rjy - riy, dz = rjz - riz;
    float r = sqrtf(dx*dx + dy*dy + dz*dz);
    float inv = 1.0f / (r + 1e-8f);
    float ux = dx*inv, uy = dy*inv, uz = dz*inv;
    float w = width[0];
    float inv2w2 = 1.0f / (2.0f * w * w);
    float* base = M0M1 + (size_t)i * 64;
    #pragma unroll
    for (int k = 0; k < 16; ++k) {
        float diff = r - centers[k];
        float b = __expf(-diff * diff * inv2w2);
        atomicAdd(base + 4*k + 0, b);
        atomicAdd(base + 4*k + 1, b * ux);
        atomicAdd(base + 4*k + 2, b * uy);
        atomicAdd(base + 4*k + 3, b * uz);
    }
}

// ---- GEMM1 fused: A = feat(M0M1) computed on the fly, B = W1, out = bf16 h1 ----
// h1 = silu(feat @ W1 + b1), feat = [M0 (16) | G1 = M1 M1^T (256)]
__global__ __launch_bounds__(256) void gemm1_fused(
    const float* __restrict__ M0M1, const float* __restrict__ B,
    const float* __restrict__ bias, __hip_bfloat16* __restrict__ C,
    int M)
{
    const int N = HID;
    __shared__ float Ms[128][68];   // per-block M0M1 rows (pad 64->68)
    __shared__ float As[16][132];
    __shared__ float Bs[16][132];
    int t = threadIdx.x;
    int tx = t & 15, ty = t >> 4;
    int row0 = blockIdx.x * 128;
    int col0 = blockIdx.y * 128;
    float acc[8][8] = {};
    int ra = t >> 2;            // A-compute row 0..63 (+64)
    int ka = (t & 3) * 4;       // A-compute k offset {0,4,8,12}
    int kb = t >> 5;            // B-load k 0..7 (+8)
    int nb = (t & 31) * 4;      // B-load col 0..124

    // stage this block's 128 M0M1 rows into LDS (each thread: half a row)
    {
        int mrow = t >> 1, mo = (t & 1) * 32;
        int gm = row0 + mrow; if (gm > M - 1) gm = M - 1;
        #pragma unroll
        for (int q = 0; q < 8; ++q)
            *(float4*)(&Ms[mrow][mo + q*4]) = *(const float4*)(M0M1 + (size_t)gm*64 + mo + q*4);
    }
    __syncthreads();

    for (int k0 = 0; k0 < NFEAT; k0 += 16) {
        int q = (k0 >> 4) - 1;   // -1 => M0 slice, else G1 row index a=q
        #pragma unroll
        for (int h = 0; h < 2; ++h) {
            int row = ra + h * 64;
            if (q < 0) {
                #pragma unroll
                for (int c = 0; c < 4; ++c)
                    As[ka+c][row] = Ms[row][4*(ka+c)];
            } else {
                float ax = Ms[row][4*q+1], ay = Ms[row][4*q+2], az = Ms[row][4*q+3];
                #pragma unroll
                for (int c = 0; c < 4; ++c) {
                    int b = ka + c;
                    As[ka+c][row] = ax*Ms[row][4*b+1] + ay*Ms[row][4*b+2] + az*Ms[row][4*b+3];
                }
            }
        }
        #pragma unroll
        for (int h = 0; h < 2; ++h) {
            int k = kb + h * 8;
            *(float4*)(&Bs[k][nb]) = *(const float4*)(B + (size_t)(k0 + k) * N + (col0 + nb));
        }
        __syncthreads();
        #pragma unroll
        for (int kk = 0; kk < 16; ++kk) {
            float a[8], b[8];
            *(float4*)(a)     = *(const float4*)(&As[kk][ty*4]);
            *(float4*)(a + 4) = *(const float4*)(&As[kk][64 + ty*4]);
            *(float4*)(b)     = *(const float4*)(&Bs[kk][tx*4]);
            *(float4*)(b + 4) = *(const float4*)(&Bs[kk][64 + tx*4]);
            #pragma unroll
            for (int i = 0; i < 8; ++i)
                #pragma unroll
                for (int jj = 0; jj < 8; ++jj)
                    acc[i][jj] += a[i] * b[jj];
        }
        __syncthreads();
    }
    float bv[8];
    #pragma unroll
    for (int jj = 0; jj < 8; ++jj)
        bv[jj] = bias[col0 + tx*4 + (jj & 3) + (jj >> 2) * 64];
    #pragma unroll
    for (int i = 0; i < 8; ++i) {
        int r = row0 + ty*4 + (i & 3) + (i >> 2) * 64;
        if (r >= M) continue;
        __hip_bfloat16 o[8];
        #pragma unroll
        for (int jj = 0; jj < 8; ++jj) {
            float c = acc[i][jj] + bv[jj];
            o[jj] = __float2bfloat16(c * (1.0f / (1.0f + __expf(-c))));
        }
        *(short4*)(C + (size_t)r * N + col0 + tx*4)      = *(short4*)(o);
        *(short4*)(C + (size_t)r * N + col0 + 64 + tx*4) = *(short4*)(o + 4);
    }
}

// ---- GEMM2 fused: h2 = silu(h1 @ W2 + b2); E += sum_r scale[Z]*(h2.W3 [+b3]) + shift ----
__global__ __launch_bounds__(256) void gemm2_reduce(
    const __hip_bfloat16* __restrict__ A, const float* __restrict__ B,
    const float* __restrict__ bias, const float* __restrict__ W3,
    const float* __restrict__ b3, const float* __restrict__ scale,
    const float* __restrict__ shift, const int* __restrict__ Z,
    float* __restrict__ out, int M)
{
    const int N = HID, K = HID;
    __shared__ float As[16][132];
    __shared__ float Bs[16][132];
    __shared__ float pw[4];
    int t = threadIdx.x;
    int tx = t & 15, ty = t >> 4;
    int row0 = blockIdx.x * 128;
    int col0 = blockIdx.y * 128;
    float acc[8][8] = {};
    int ra = t >> 2;
    int ka = (t & 3) * 4;
    int kb = t >> 5;
    int nb = (t & 31) * 4;

    for (int k0 = 0; k0 < K; k0 += 16) {
        #pragma unroll
        for (int h = 0; h < 2; ++h) {
            int row = ra + h * 64;
            int grow = row0 + row; if (grow > M - 1) grow = M - 1;
            short4 av = *(const short4*)(A + (size_t)grow * K + (k0 + ka));
            const __hip_bfloat16* ab = (const __hip_bfloat16*)&av;
            As[ka+0][row] = __bfloat162float(ab[0]);
            As[ka+1][row] = __bfloat162float(ab[1]);
            As[ka+2][row] = __bfloat162float(ab[2]);
            As[ka+3][row] = __bfloat162float(ab[3]);
        }
        #pragma unroll
        for (int h = 0; h < 2; ++h) {
            int k = kb + h * 8;
            *(float4*)(&Bs[k][nb]) = *(const float4*)(B + (size_t)(k0 + k) * N + (col0 + nb));
        }
        __syncthreads();
        #pragma unroll
        for (int kk = 0; kk < 16; ++kk) {
            float a[8], b[8];
            *(float4*)(a)     = *(const float4*)(&As[kk][ty*4]);
            *(float4*)(a + 4) = *(const float4*)(&As[kk][64 + ty*4]);
            *(float4*)(b)     = *(const float4*)(&Bs[kk][tx*4]);
            *(float4*)(b + 4) = *(const float4*)(&Bs[kk][64 + tx*4]);
            #pragma unroll
            for (int i = 0; i < 8; ++i)
                #pragma unroll
                for (int jj = 0; jj < 8; ++jj)
                    acc[i][jj] += a[i] * b[jj];
        }
        __syncthreads();
    }
    float bv[8], w3v[8];
    #pragma unroll
    for (int jj = 0; jj < 8; ++jj) {
        int col = col0 + tx*4 + (jj & 3) + (jj >> 2) * 64;
        bv[jj]  = bias[col];
        w3v[jj] = W3[col];
    }
    // per-row partial dot with W3 over this block's 128 cols
    float rowacc[8];
    #pragma unroll
    for (int i = 0; i < 8; ++i) {
        float s = 0.0f;
        #pragma unroll
        for (int jj = 0; jj < 8; ++jj) {
            float c = acc[i][jj] + bv[jj];
            s += (c * (1.0f / (1.0f + __expf(-c)))) * w3v[jj];
        }
        rowacc[i] = s;
    }
    // reduce across the 16 tx threads sharing each row (16 consecutive lanes)
    #pragma unroll
    for (int i = 0; i < 8; ++i)
        #pragma unroll
        for (int off = 1; off < 16; off <<= 1)
            rowacc[i] += __shfl_xor(rowacc[i], off);
    float e = 0.0f;
    if (tx == 0) {
        #pragma unroll
        for (int i = 0; i < 8; ++i) {
            int r = row0 + ty*4 + (i & 3) + (i >> 2) * 64;
            if (r < M) {
                int z = Z[r];
                e += scale[z] * rowacc[i];
                if (blockIdx.y == 0) e += scale[z] * b3[0] + shift[z];
            }
        }
    }
    // block reduce + single atomic
    #pragma unroll
    for (int off = 32; off > 0; off >>= 1) e += __shfl_down(e, off);
    int wv = t >> 6, lane = t & 63;
    if (lane == 0) pw[wv] = e;
    __syncthreads();
    if (t == 0) atomicAdd(out, pw[0] + pw[1] + pw[2] + pw[3]);
}

extern "C" void kernel_launch(void* const* d_in, const int* in_sizes, int n_in,
                              void* d_out, int out_size, void* d_ws, size_t ws_size,
                              hipStream_t stream)
{
    const float* R       = (const float*)d_in[0];
    const int*   Z       = (const int*)  d_in[1];
    const int*   idx     = (const int*)  d_in[2];
    // d_in[3] box, d_in[4] offsets: unused (free-space displacement, zero offsets)
    const float* centers = (const float*)d_in[5];
    const float* width   = (const float*)d_in[6];
    const float* W1      = (const float*)d_in[7];
    const float* b1      = (const float*)d_in[8];
    const float* W2      = (const float*)d_in[9];
    const float* b2      = (const float*)d_in[10];
    const float* W3      = (const float*)d_in[11];
    const float* b3      = (const float*)d_in[12];
    const float* scale   = (const float*)d_in[13];
    const float* shift   = (const float*)d_in[14];

    int nAtoms = in_sizes[0] / 3;
    int nEdges = in_sizes[2] / 2;

    size_t m0m1_bytes = (size_t)nAtoms * 64 * sizeof(float);        // 25.6 MB
    size_t h1_bytes   = (size_t)nAtoms * HID * sizeof(__hip_bfloat16); // 102.4 MB
    if (ws_size < m0m1_bytes + h1_bytes) return;  // ws too small: leave out=0 (clean fail, no fault)

    char* ws = (char*)d_ws;
    float* M0M1        = (float*)ws;
    __hip_bfloat16* h1 = (__hip_bfloat16*)(ws + m0m1_bytes);
    float* out         = (float*)d_out;

    hipMemsetAsync(M0M1, 0, m0m1_bytes, stream);
    hipMemsetAsync(out, 0, sizeof(float), stream);

    edge_kernel<<<(nEdges + 255) / 256, 256, 0, stream>>>(R, idx, centers, width, M0M1, nEdges);
    dim3 g((nAtoms + 127) / 128, 4);
    gemm1_fused<<<g, 256, 0, stream>>>(M0M1, W1, b1, h1, nAtoms);
    gemm2_reduce<<<g, 256, 0, stream>>>(h1, W2, b2, W3, b3, scale, shift, Z, out, nAtoms);
}

// Round 3
// 1352.705 us; speedup vs baseline: 4.8111x; 4.8111x over previous
//
#include <hip/hip_runtime.h>
#include <hip/hip_bf16.h>
#include <cstdint>

#define NFEAT 272
#define HID 512

// ---------- 1) histogram: edges per destination atom ----------
__global__ __launch_bounds__(256) void hist_kernel(
    const int* __restrict__ idx, int* __restrict__ counts, int nEdges)
{
    int e = blockIdx.x * 256 + threadIdx.x;
    if (e < nEdges) atomicAdd(&counts[idx[e]], 1);
}

// ---------- 2) exclusive scan (single block, 1024 thr, shuffle-based) ----------
__global__ __launch_bounds__(1024) void scan_kernel(
    const int* __restrict__ counts, int* __restrict__ starts,
    int* __restrict__ cursor, int n)
{
    __shared__ int wsum[16];
    __shared__ int carry;
    int t = threadIdx.x, lane = t & 63, wid = t >> 6;
    if (t == 0) carry = 0;
    __syncthreads();
    for (int base = 0; base < n; base += 1024) {
        int i = base + t;
        int v = (i < n) ? counts[i] : 0;
        int incl = v;
        #pragma unroll
        for (int off = 1; off < 64; off <<= 1) {
            int u = __shfl_up(incl, off);
            if (lane >= off) incl += u;
        }
        if (lane == 63) wsum[wid] = incl;
        __syncthreads();
        if (t < 16) {
            int s = wsum[t];
            #pragma unroll
            for (int off = 1; off < 16; off <<= 1) {
                int u = __shfl_up(s, off);
                if (t >= off) s += u;
            }
            wsum[t] = s;   // inclusive wave sums
        }
        __syncthreads();
        int woff = (wid == 0) ? 0 : wsum[wid - 1];
        int excl = carry + woff + incl - v;
        if (i < n) { starts[i] = excl; cursor[i] = excl; }
        __syncthreads();
        if (t == 0) carry += wsum[15];
        __syncthreads();
    }
    if (t == 0) starts[n] = carry;
}

// ---------- 3) scatter: per-edge geometry -> segment-sorted float4 ----------
__global__ __launch_bounds__(256) void scatter_kernel(
    const float* __restrict__ R, const int* __restrict__ idx,
    int* __restrict__ cursor, float4* __restrict__ sorted, int nEdges)
{
    int e = blockIdx.x * 256 + threadIdx.x;
    if (e >= nEdges) return;
    int i = idx[e];
    int j = idx[nEdges + e];
    float rix = R[3*(size_t)i], riy = R[3*(size_t)i+1], riz = R[3*(size_t)i+2];
    float rjx = R[3*(size_t)j], rjy = R[3*(size_t)j+1], rjz = R[3*(size_t)j+2];
    float dx = rjx - rix, dy = rjy - riy, dz = rjz - riz;
    float r = sqrtf(dx*dx + dy*dy + dz*dz);
    float inv = 1.0f / (r + 1e-8f);
    int pos = atomicAdd(&cursor[i], 1);
    sorted[pos] = make_float4(r, dx*inv, dy*inv, dz*inv);
}

// ---------- 4) segmented reduce: one wave per atom, lane = (k,comp) ----------
__global__ __launch_bounds__(256) void accum_kernel(
    const float4* __restrict__ sorted, const int* __restrict__ starts,
    const float* __restrict__ centers, const float* __restrict__ width,
    float* __restrict__ M0M1, int nAtoms)
{
    int wv = threadIdx.x >> 6, lane = threadIdx.x & 63;
    int atom = blockIdx.x * 4 + wv;
    if (atom >= nAtoms) return;
    int s = starts[atom], e = starts[atom + 1];
    int k = lane >> 2, c = lane & 3;
    float ck = centers[k];
    float w = width[0];
    float inv2w2 = 1.0f / (2.0f * w * w);
    float acc = 0.0f;
    for (int p = s; p < e; ++p) {
        float4 v = sorted[p];                       // broadcast load
        float diff = v.x - ck;
        float b = __expf(-diff * diff * inv2w2);
        float comp = (c == 0) ? 1.0f : ((c == 1) ? v.y : ((c == 2) ? v.z : v.w));
        acc += b * comp;
    }
    M0M1[(size_t)atom * 64 + lane] = acc;
}

// ---- GEMM1 fused: A = feat(M0M1) computed on the fly, B = W1, out = bf16 h1 ----
// h1 = silu(feat @ W1 + b1), feat = [M0 (16) | G1 = M1 M1^T (256)]
__global__ __launch_bounds__(256) void gemm1_fused(
    const float* __restrict__ M0M1, const float* __restrict__ B,
    const float* __restrict__ bias, __hip_bfloat16* __restrict__ C,
    int M)
{
    const int N = HID;
    __shared__ float Ms[128][68];   // per-block M0M1 rows (pad 64->68)
    __shared__ float As[16][132];
    __shared__ float Bs[16][132];
    int t = threadIdx.x;
    int tx = t & 15, ty = t >> 4;
    int row0 = blockIdx.x * 128;
    int col0 = blockIdx.y * 128;
    float acc[8][8] = {};
    int ra = t >> 2;            // A-compute row 0..63 (+64)
    int ka = (t & 3) * 4;       // A-compute k offset {0,4,8,12}
    int kb = t >> 5;            // B-load k 0..7 (+8)
    int nb = (t & 31) * 4;      // B-load col 0..124

    {
        int mrow = t >> 1, mo = (t & 1) * 32;
        int gm = row0 + mrow; if (gm > M - 1) gm = M - 1;
        #pragma unroll
        for (int q = 0; q < 8; ++q)
            *(float4*)(&Ms[mrow][mo + q*4]) = *(const float4*)(M0M1 + (size_t)gm*64 + mo + q*4);
    }
    __syncthreads();

    for (int k0 = 0; k0 < NFEAT; k0 += 16) {
        int q = (k0 >> 4) - 1;   // -1 => M0 slice, else G1 row index a=q
        #pragma unroll
        for (int h = 0; h < 2; ++h) {
            int row = ra + h * 64;
            if (q < 0) {
                #pragma unroll
                for (int c = 0; c < 4; ++c)
                    As[ka+c][row] = Ms[row][4*(ka+c)];
            } else {
                float ax = Ms[row][4*q+1], ay = Ms[row][4*q+2], az = Ms[row][4*q+3];
                #pragma unroll
                for (int c = 0; c < 4; ++c) {
                    int b = ka + c;
                    As[ka+c][row] = ax*Ms[row][4*b+1] + ay*Ms[row][4*b+2] + az*Ms[row][4*b+3];
                }
            }
        }
        #pragma unroll
        for (int h = 0; h < 2; ++h) {
            int k = kb + h * 8;
            *(float4*)(&Bs[k][nb]) = *(const float4*)(B + (size_t)(k0 + k) * N + (col0 + nb));
        }
        __syncthreads();
        #pragma unroll
        for (int kk = 0; kk < 16; ++kk) {
            float a[8], b[8];
            *(float4*)(a)     = *(const float4*)(&As[kk][ty*4]);
            *(float4*)(a + 4) = *(const float4*)(&As[kk][64 + ty*4]);
            *(float4*)(b)     = *(const float4*)(&Bs[kk][tx*4]);
            *(float4*)(b + 4) = *(const float4*)(&Bs[kk][64 + tx*4]);
            #pragma unroll
            for (int i = 0; i < 8; ++i)
                #pragma unroll
                for (int jj = 0; jj < 8; ++jj)
                    acc[i][jj] += a[i] * b[jj];
        }
        __syncthreads();
    }
    float bv[8];
    #pragma unroll
    for (int jj = 0; jj < 8; ++jj)
        bv[jj] = bias[col0 + tx*4 + (jj & 3) + (jj >> 2) * 64];
    #pragma unroll
    for (int i = 0; i < 8; ++i) {
        int r = row0 + ty*4 + (i & 3) + (i >> 2) * 64;
        if (r >= M) continue;
        __hip_bfloat16 o[8];
        #pragma unroll
        for (int jj = 0; jj < 8; ++jj) {
            float c = acc[i][jj] + bv[jj];
            o[jj] = __float2bfloat16(c * (1.0f / (1.0f + __expf(-c))));
        }
        *(short4*)(C + (size_t)r * N + col0 + tx*4)      = *(short4*)(o);
        *(short4*)(C + (size_t)r * N + col0 + 64 + tx*4) = *(short4*)(o + 4);
    }
}

// ---- GEMM2 fused: h2 = silu(h1 @ W2 + b2); E += sum_r scale[Z]*(h2.W3 [+b3]) + shift ----
__global__ __launch_bounds__(256) void gemm2_reduce(
    const __hip_bfloat16* __restrict__ A, const float* __restrict__ B,
    const float* __restrict__ bias, const float* __restrict__ W3,
    const float* __restrict__ b3, const float* __restrict__ scale,
    const float* __restrict__ shift, const int* __restrict__ Z,
    float* __restrict__ out, int M)
{
    const int N = HID, K = HID;
    __shared__ float As[16][132];
    __shared__ float Bs[16][132];
    __shared__ float pw[4];
    int t = threadIdx.x;
    int tx = t & 15, ty = t >> 4;
    int row0 = blockIdx.x * 128;
    int col0 = blockIdx.y * 128;
    float acc[8][8] = {};
    int ra = t >> 2;
    int ka = (t & 3) * 4;
    int kb = t >> 5;
    int nb = (t & 31) * 4;

    for (int k0 = 0; k0 < K; k0 += 16) {
        #pragma unroll
        for (int h = 0; h < 2; ++h) {
            int row = ra + h * 64;
            int grow = row0 + row; if (grow > M - 1) grow = M - 1;
            short4 av = *(const short4*)(A + (size_t)grow * K + (k0 + ka));
            const __hip_bfloat16* ab = (const __hip_bfloat16*)&av;
            As[ka+0][row] = __bfloat162float(ab[0]);
            As[ka+1][row] = __bfloat162float(ab[1]);
            As[ka+2][row] = __bfloat162float(ab[2]);
            As[ka+3][row] = __bfloat162float(ab[3]);
        }
        #pragma unroll
        for (int h = 0; h < 2; ++h) {
            int k = kb + h * 8;
            *(float4*)(&Bs[k][nb]) = *(const float4*)(B + (size_t)(k0 + k) * N + (col0 + nb));
        }
        __syncthreads();
        #pragma unroll
        for (int kk = 0; kk < 16; ++kk) {
            float a[8], b[8];
            *(float4*)(a)     = *(const float4*)(&As[kk][ty*4]);
            *(float4*)(a + 4) = *(const float4*)(&As[kk][64 + ty*4]);
            *(float4*)(b)     = *(const float4*)(&Bs[kk][tx*4]);
            *(float4*)(b + 4) = *(const float4*)(&Bs[kk][64 + tx*4]);
            #pragma unroll
            for (int i = 0; i < 8; ++i)
                #pragma unroll
                for (int jj = 0; jj < 8; ++jj)
                    acc[i][jj] += a[i] * b[jj];
        }
        __syncthreads();
    }
    float bv[8], w3v[8];
    #pragma unroll
    for (int jj = 0; jj < 8; ++jj) {
        int col = col0 + tx*4 + (jj & 3) + (jj >> 2) * 64;
        bv[jj]  = bias[col];
        w3v[jj] = W3[col];
    }
    float rowacc[8];
    #pragma unroll
    for (int i = 0; i < 8; ++i) {
        float s = 0.0f;
        #pragma unroll
        for (int jj = 0; jj < 8; ++jj) {
            float c = acc[i][jj] + bv[jj];
            s += (c * (1.0f / (1.0f + __expf(-c)))) * w3v[jj];
        }
        rowacc[i] = s;
    }
    #pragma unroll
    for (int i = 0; i < 8; ++i)
        #pragma unroll
        for (int off = 1; off < 16; off <<= 1)
            rowacc[i] += __shfl_xor(rowacc[i], off);
    float e = 0.0f;
    if (tx == 0) {
        #pragma unroll
        for (int i = 0; i < 8; ++i) {
            int r = row0 + ty*4 + (i & 3) + (i >> 2) * 64;
            if (r < M) {
                int z = Z[r];
                e += scale[z] * rowacc[i];
                if (blockIdx.y == 0) e += scale[z] * b3[0] + shift[z];
            }
        }
    }
    #pragma unroll
    for (int off = 32; off > 0; off >>= 1) e += __shfl_down(e, off);
    int wv = t >> 6, lane = t & 63;
    if (lane == 0) pw[wv] = e;
    __syncthreads();
    if (t == 0) atomicAdd(out, pw[0] + pw[1] + pw[2] + pw[3]);
}

extern "C" void kernel_launch(void* const* d_in, const int* in_sizes, int n_in,
                              void* d_out, int out_size, void* d_ws, size_t ws_size,
                              hipStream_t stream)
{
    const float* R       = (const float*)d_in[0];
    const int*   Z       = (const int*)  d_in[1];
    const int*   idx     = (const int*)  d_in[2];
    const float* centers = (const float*)d_in[5];
    const float* width   = (const float*)d_in[6];
    const float* W1      = (const float*)d_in[7];
    const float* b1      = (const float*)d_in[8];
    const float* W2      = (const float*)d_in[9];
    const float* b2      = (const float*)d_in[10];
    const float* W3      = (const float*)d_in[11];
    const float* b3      = (const float*)d_in[12];
    const float* scale   = (const float*)d_in[13];
    const float* shift   = (const float*)d_in[14];

    int nAtoms = in_sizes[0] / 3;
    int nEdges = in_sizes[2] / 2;

    size_t m0m1_bytes = (size_t)nAtoms * 64 * sizeof(float);           // 25.6 MB
    size_t h1_bytes   = (size_t)nAtoms * HID * sizeof(__hip_bfloat16); // 102.4 MB
    if (ws_size < m0m1_bytes + h1_bytes) return;  // clean fail, no fault

    char* ws = (char*)d_ws;
    float* M0M1        = (float*)ws;
    char*  regB        = ws + m0m1_bytes;                  // h1 region (102.4 MB)
    __hip_bfloat16* h1 = (__hip_bfloat16*)regB;

    // sort scratch aliased into regB: dead before gemm1 writes h1
    size_t sorted_bytes = (size_t)nEdges * sizeof(float4);             // 25.6 MB
    float4* sorted = (float4*)regB;
    int* counts = (int*)(regB + sorted_bytes);
    int* starts = counts + nAtoms;          // nAtoms+1 ints
    int* cursor = starts + nAtoms + 1;
    size_t sort_total = sorted_bytes + (size_t)(3 * nAtoms + 1) * sizeof(int);
    if (sort_total > h1_bytes) return;

    float* out = (float*)d_out;

    hipMemsetAsync(counts, 0, (size_t)nAtoms * sizeof(int), stream);
    hipMemsetAsync(out, 0, sizeof(float), stream);

    int eb = (nEdges + 255) / 256;
    hist_kernel   <<<eb, 256, 0, stream>>>(idx, counts, nEdges);
    scan_kernel   <<<1, 1024, 0, stream>>>(counts, starts, cursor, nAtoms);
    scatter_kernel<<<eb, 256, 0, stream>>>(R, idx, cursor, sorted, nEdges);
    accum_kernel  <<<(nAtoms + 3) / 4, 256, 0, stream>>>(sorted, starts, centers, width, M0M1, nAtoms);

    dim3 g((nAtoms + 127) / 128, 4);
    gemm1_fused <<<g, 256, 0, stream>>>(M0M1, W1, b1, h1, nAtoms);
    gemm2_reduce<<<g, 256, 0, stream>>>(h1, W2, b2, W3, b3, scale, shift, Z, out, nAtoms);
}

// Round 4
// 632.085 us; speedup vs baseline: 10.2960x; 2.1401x over previous
//
#include <hip/hip_runtime.h>
#include <hip/hip_bf16.h>
#include <cstdint>

#define HID 512
#define K1P 288   // feat K padded 272 -> 288

typedef __attribute__((ext_vector_type(8))) short bf16x8;
typedef __attribute__((ext_vector_type(4))) float f32x4;

__device__ __forceinline__ short f2bf(float x) {
    __hip_bfloat16 h = __float2bfloat16(x);
    return *(short*)&h;
}
__device__ __forceinline__ float silu(float x) {
    return x * (1.0f / (1.0f + __expf(-x)));
}
__device__ __forceinline__ void gl_lds16(const void* src, void* dst) {
    __builtin_amdgcn_global_load_lds(
        (const __attribute__((address_space(1))) void*)src,
        (__attribute__((address_space(3))) void*)dst, 16, 0, 0);
}

// ---------- 1) histogram ----------
__global__ __launch_bounds__(256) void hist_kernel(
    const int* __restrict__ idx, int* __restrict__ counts, int nEdges)
{
    int e = blockIdx.x * 256 + threadIdx.x;
    if (e < nEdges) atomicAdd(&counts[idx[e]], 1);
}

// ---------- 2) exclusive scan (single block) ----------
__global__ __launch_bounds__(1024) void scan_kernel(
    const int* __restrict__ counts, int* __restrict__ starts,
    int* __restrict__ cursor, int n)
{
    __shared__ int wsum[16];
    __shared__ int carry;
    int t = threadIdx.x, lane = t & 63, wid = t >> 6;
    if (t == 0) carry = 0;
    __syncthreads();
    for (int base = 0; base < n; base += 1024) {
        int i = base + t;
        int v = (i < n) ? counts[i] : 0;
        int incl = v;
        #pragma unroll
        for (int off = 1; off < 64; off <<= 1) {
            int u = __shfl_up(incl, off);
            if (lane >= off) incl += u;
        }
        if (lane == 63) wsum[wid] = incl;
        __syncthreads();
        if (t < 16) {
            int s = wsum[t];
            #pragma unroll
            for (int off = 1; off < 16; off <<= 1) {
                int u = __shfl_up(s, off);
                if (t >= off) s += u;
            }
            wsum[t] = s;
        }
        __syncthreads();
        int woff = (wid == 0) ? 0 : wsum[wid - 1];
        int excl = carry + woff + incl - v;
        if (i < n) { starts[i] = excl; cursor[i] = excl; }
        __syncthreads();
        if (t == 0) carry += wsum[15];
        __syncthreads();
    }
    if (t == 0) starts[n] = carry;
}

// ---------- 3) scatter ----------
__global__ __launch_bounds__(256) void scatter_kernel(
    const float* __restrict__ R, const int* __restrict__ idx,
    int* __restrict__ cursor, float4* __restrict__ sorted, int nEdges)
{
    int e = blockIdx.x * 256 + threadIdx.x;
    if (e >= nEdges) return;
    int i = idx[e];
    int j = idx[nEdges + e];
    float rix = R[3*(size_t)i], riy = R[3*(size_t)i+1], riz = R[3*(size_t)i+2];
    float rjx = R[3*(size_t)j], rjy = R[3*(size_t)j+1], rjz = R[3*(size_t)j+2];
    float dx = rjx - rix, dy = rjy - riy, dz = rjz - riz;
    float r = sqrtf(dx*dx + dy*dy + dz*dz);
    float inv = 1.0f / (r + 1e-8f);
    int pos = atomicAdd(&cursor[i], 1);
    sorted[pos] = make_float4(r, dx*inv, dy*inv, dz*inv);
}

// ---------- 4) segmented reduce ----------
__global__ __launch_bounds__(256) void accum_kernel(
    const float4* __restrict__ sorted, const int* __restrict__ starts,
    const float* __restrict__ centers, const float* __restrict__ width,
    float* __restrict__ M0M1, int nAtoms)
{
    int wv = threadIdx.x >> 6, lane = threadIdx.x & 63;
    int atom = blockIdx.x * 4 + wv;
    if (atom >= nAtoms) return;
    int s = starts[atom], e = starts[atom + 1];
    int k = lane >> 2, c = lane & 3;
    float ck = centers[k];
    float w = width[0];
    float inv2w2 = 1.0f / (2.0f * w * w);
    float acc = 0.0f;
    for (int p = s; p < e; ++p) {
        float4 v = sorted[p];
        float diff = v.x - ck;
        float b = __expf(-diff * diff * inv2w2);
        float comp = (c == 0) ? 1.0f : ((c == 1) ? v.y : ((c == 2) ? v.z : v.w));
        acc += b * comp;
    }
    M0M1[(size_t)atom * 64 + lane] = acc;
}

// ---------- W -> bf16 transposed (Wt[n][kpad]) ----------
__global__ __launch_bounds__(256) void convW_kernel(
    const float* __restrict__ W, short* __restrict__ Wt, int K, int Kpad, int N)
{
    int n = blockIdx.x * 256 + threadIdx.x;
    int k = blockIdx.y;
    if (n >= N) return;
    float v = (k < K) ? W[(size_t)k * N + n] : 0.0f;
    Wt[(size_t)n * Kpad + k] = f2bf(v);
}

// ---------- GEMM1 MFMA: h1 = silu(feat @ W1 + b1), feat computed on the fly ----------
__global__ __launch_bounds__(256) void gemm1_mfma(
    const float* __restrict__ M0M1, const short* __restrict__ W1t,
    const float* __restrict__ bias, short* __restrict__ C, int M)
{
    __shared__ float MsT[64][128];     // transposed M0M1: [comp][row]
    __shared__ short Asl[4 * 128 * 8];
    __shared__ short Bsl[4 * 128 * 8];
    int t = threadIdx.x;
    int w = t >> 6, lane = t & 63;
    int wr = w >> 1, wc = w & 1;
    int li = lane & 15, lg = lane >> 4;
    int row0 = blockIdx.x * 128, col0 = blockIdx.y * 128;

    // stage M0M1 transposed into LDS
    {
        int mrow = t >> 1, mo = (t & 1) * 32;
        int gm = row0 + mrow; if (gm > M - 1) gm = M - 1;
        const float4* src = (const float4*)(M0M1 + (size_t)gm * 64 + mo);
        #pragma unroll
        for (int q = 0; q < 8; ++q) {
            float4 v = src[q];
            int c0 = mo + q * 4;
            MsT[c0+0][mrow] = v.x; MsT[c0+1][mrow] = v.y;
            MsT[c0+2][mrow] = v.z; MsT[c0+3][mrow] = v.w;
        }
    }
    f32x4 zz = {0.f, 0.f, 0.f, 0.f};
    f32x4 acc[4][4];
    #pragma unroll
    for (int m = 0; m < 4; ++m)
        #pragma unroll
        for (int n = 0; n < 4; ++n) acc[m][n] = zz;
    __syncthreads();

    for (int k0 = 0; k0 < K1P; k0 += 32) {
        // A tile: compute feat -> bf16 -> Asl[(k8*128+row)*8]
        #pragma unroll
        for (int c = 0; c < 2; ++c) {
            int cell = c * 256 + t;
            int k8 = cell >> 7, row = cell & 127;
            int kbase = k0 + k8 * 8;
            bf16x8 v;
            if (kbase < 16) {
                #pragma unroll
                for (int j = 0; j < 8; ++j) v[j] = f2bf(MsT[4*(kbase+j)][row]);
            } else if (kbase < 272) {
                int g = kbase - 16, a = g >> 4, b0 = g & 15;
                float ax = MsT[4*a+1][row], ay = MsT[4*a+2][row], az = MsT[4*a+3][row];
                #pragma unroll
                for (int j = 0; j < 8; ++j) {
                    int b = b0 + j;
                    v[j] = f2bf(ax*MsT[4*b+1][row] + ay*MsT[4*b+2][row] + az*MsT[4*b+3][row]);
                }
            } else {
                #pragma unroll
                for (int j = 0; j < 8; ++j) v[j] = 0;
            }
            *(bf16x8*)&Asl[cell * 8] = v;
        }
        // B tile: global_load_lds from W1t
        #pragma unroll
        for (int p = 0; p < 2; ++p) {
            int cell = (w * 2 + p) * 64 + lane;
            int k8 = cell >> 7, n = cell & 127;
            const short* src = W1t + (size_t)(col0 + n) * K1P + k0 + k8 * 8;
            gl_lds16(src, &Bsl[(w * 2 + p) * 64 * 8]);
        }
        __syncthreads();
        bf16x8 af[4], bfr[4];
        const short* Ab = &Asl[(lg * 128 + wr * 64 + li) * 8];
        const short* Bb = &Bsl[(lg * 128 + wc * 64 + li) * 8];
        #pragma unroll
        for (int m = 0; m < 4; ++m) af[m] = *(const bf16x8*)(Ab + m * 128);
        #pragma unroll
        for (int n = 0; n < 4; ++n) bfr[n] = *(const bf16x8*)(Bb + n * 128);
        #pragma unroll
        for (int m = 0; m < 4; ++m)
            #pragma unroll
            for (int n = 0; n < 4; ++n)
                acc[m][n] = __builtin_amdgcn_mfma_f32_16x16x32_bf16(af[m], bfr[n], acc[m][n], 0, 0, 0);
        __syncthreads();
    }

    float bv[4];
    #pragma unroll
    for (int n = 0; n < 4; ++n) bv[n] = bias[col0 + wc * 64 + n * 16 + li];
    #pragma unroll
    for (int m = 0; m < 4; ++m)
        #pragma unroll
        for (int r = 0; r < 4; ++r) {
            int row = row0 + wr * 64 + m * 16 + lg * 4 + r;
            if (row >= M) continue;
            size_t base = (size_t)row * HID + col0 + wc * 64 + li;
            #pragma unroll
            for (int n = 0; n < 4; ++n) {
                float cx = acc[m][n][r] + bv[n];
                C[base + n * 16] = f2bf(silu(cx));
            }
        }
}

// ---------- GEMM2 MFMA + fused W3/scale/shift/total-energy reduce ----------
__global__ __launch_bounds__(256) void gemm2_mfma(
    const short* __restrict__ A, const short* __restrict__ W2t,
    const float* __restrict__ bias, const float* __restrict__ W3,
    const float* __restrict__ b3, const float* __restrict__ scale,
    const float* __restrict__ shift, const int* __restrict__ Z,
    float* __restrict__ out, int M)
{
    __shared__ short Asl[4 * 128 * 8];
    __shared__ short Bsl[4 * 128 * 8];
    __shared__ float rsum[2][128];
    __shared__ float red[2];
    int t = threadIdx.x;
    int w = t >> 6, lane = t & 63;
    int wr = w >> 1, wc = w & 1;
    int li = lane & 15, lg = lane >> 4;
    int row0 = blockIdx.x * 128, col0 = blockIdx.y * 128;

    f32x4 zz = {0.f, 0.f, 0.f, 0.f};
    f32x4 acc[4][4];
    #pragma unroll
    for (int m = 0; m < 4; ++m)
        #pragma unroll
        for (int n = 0; n < 4; ++n) acc[m][n] = zz;

    for (int k0 = 0; k0 < HID; k0 += 32) {
        #pragma unroll
        for (int p = 0; p < 2; ++p) {
            int cell = (w * 2 + p) * 64 + lane;
            int k8 = cell >> 7, row = cell & 127;
            int gr = row0 + row; if (gr > M - 1) gr = M - 1;
            const short* src = A + (size_t)gr * HID + k0 + k8 * 8;
            gl_lds16(src, &Asl[(w * 2 + p) * 64 * 8]);
        }
        #pragma unroll
        for (int p = 0; p < 2; ++p) {
            int cell = (w * 2 + p) * 64 + lane;
            int k8 = cell >> 7, n = cell & 127;
            const short* src = W2t + (size_t)(col0 + n) * HID + k0 + k8 * 8;
            gl_lds16(src, &Bsl[(w * 2 + p) * 64 * 8]);
        }
        __syncthreads();
        bf16x8 af[4], bfr[4];
        const short* Ab = &Asl[(lg * 128 + wr * 64 + li) * 8];
        const short* Bb = &Bsl[(lg * 128 + wc * 64 + li) * 8];
        #pragma unroll
        for (int m = 0; m < 4; ++m) af[m] = *(const bf16x8*)(Ab + m * 128);
        #pragma unroll
        for (int n = 0; n < 4; ++n) bfr[n] = *(const bf16x8*)(Bb + n * 128);
        #pragma unroll
        for (int m = 0; m < 4; ++m)
            #pragma unroll
            for (int n = 0; n < 4; ++n)
                acc[m][n] = __builtin_amdgcn_mfma_f32_16x16x32_bf16(af[m], bfr[n], acc[m][n], 0, 0, 0);
        __syncthreads();
    }

    float bv[4], w3v[4];
    #pragma unroll
    for (int n = 0; n < 4; ++n) {
        int col = col0 + wc * 64 + n * 16 + li;
        bv[n] = bias[col];
        w3v[n] = W3[col];
    }
    #pragma unroll
    for (int m = 0; m < 4; ++m)
        #pragma unroll
        for (int r = 0; r < 4; ++r) {
            float s = 0.f;
            #pragma unroll
            for (int n = 0; n < 4; ++n) {
                float cx = acc[m][n][r] + bv[n];
                s += silu(cx) * w3v[n];
            }
            #pragma unroll
            for (int off = 1; off < 16; off <<= 1) s += __shfl_xor(s, off);
            if (li == 0) rsum[wc][wr * 64 + m * 16 + lg * 4 + r] = s;
        }
    __syncthreads();
    float e = 0.f;
    if (t < 128) {
        int row = row0 + t;
        if (row < M) {
            float v = rsum[0][t] + rsum[1][t];
            int z = Z[row];
            e = scale[z] * v;
            if (blockIdx.y == 0) e += scale[z] * b3[0] + shift[z];
        }
        #pragma unroll
        for (int off = 32; off > 0; off >>= 1) e += __shfl_down(e, off);
        if ((t & 63) == 0) red[t >> 6] = e;
    }
    __syncthreads();
    if (t == 0) atomicAdd(out, red[0] + red[1]);
}

extern "C" void kernel_launch(void* const* d_in, const int* in_sizes, int n_in,
                              void* d_out, int out_size, void* d_ws, size_t ws_size,
                              hipStream_t stream)
{
    const float* R       = (const float*)d_in[0];
    const int*   Z       = (const int*)  d_in[1];
    const int*   idx     = (const int*)  d_in[2];
    const float* centers = (const float*)d_in[5];
    const float* width   = (const float*)d_in[6];
    const float* W1      = (const float*)d_in[7];
    const float* b1      = (const float*)d_in[8];
    const float* W2      = (const float*)d_in[9];
    const float* b2      = (const float*)d_in[10];
    const float* W3      = (const float*)d_in[11];
    const float* b3      = (const float*)d_in[12];
    const float* scale   = (const float*)d_in[13];
    const float* shift   = (const float*)d_in[14];

    int nAtoms = in_sizes[0] / 3;
    int nEdges = in_sizes[2] / 2;

    size_t m0m1_b = (size_t)nAtoms * 64 * sizeof(float);   // 25.6 MB
    size_t h1_b   = (size_t)nAtoms * HID * 2;              // 102.4 MB
    size_t w1t_b  = (size_t)HID * K1P * 2;                 // 288 KB
    size_t w2t_b  = (size_t)HID * HID * 2;                 // 512 KB
    if (ws_size < m0m1_b + h1_b + w1t_b + w2t_b) return;   // clean fail, no fault

    char* ws = (char*)d_ws;
    float* M0M1 = (float*)ws;
    char*  regB = ws + m0m1_b;
    short* h1   = (short*)regB;
    short* W1t  = (short*)(ws + m0m1_b + h1_b);
    short* W2t  = W1t + (size_t)HID * K1P;

    // sort scratch aliased into regB (dead before gemm1 writes h1)
    size_t sorted_b = (size_t)nEdges * sizeof(float4);
    float4* sorted = (float4*)regB;
    int* counts = (int*)(regB + sorted_b);
    int* starts = counts + nAtoms;
    int* cursor = starts + nAtoms + 1;
    if (sorted_b + (size_t)(3 * nAtoms + 1) * sizeof(int) > h1_b) return;

    float* out = (float*)d_out;

    hipMemsetAsync(counts, 0, (size_t)nAtoms * sizeof(int), stream);
    hipMemsetAsync(out, 0, sizeof(float), stream);

    convW_kernel<<<dim3(2, K1P), 256, 0, stream>>>(W1, W1t, 272, K1P, HID);
    convW_kernel<<<dim3(2, HID), 256, 0, stream>>>(W2, W2t, HID, HID, HID);

    int eb = (nEdges + 255) / 256;
    hist_kernel   <<<eb, 256, 0, stream>>>(idx, counts, nEdges);
    scan_kernel   <<<1, 1024, 0, stream>>>(counts, starts, cursor, nAtoms);
    scatter_kernel<<<eb, 256, 0, stream>>>(R, idx, cursor, sorted, nEdges);
    accum_kernel  <<<(nAtoms + 3) / 4, 256, 0, stream>>>(sorted, starts, centers, width, M0M1, nAtoms);

    dim3 g((nAtoms + 127) / 128, 4);
    gemm1_mfma<<<g, 256, 0, stream>>>(M0M1, W1t, b1, h1, nAtoms);
    gemm2_mfma<<<g, 256, 0, stream>>>(h1, W2t, b2, W3, b3, scale, shift, Z, out, nAtoms);
}

// Round 5
// 595.573 us; speedup vs baseline: 10.9272x; 1.0613x over previous
//
#include <hip/hip_runtime.h>
#include <hip/hip_bf16.h>
#include <cstdint>

#define HID 512
#define K1P 288   // feat K padded 272 -> 288

typedef __attribute__((ext_vector_type(8))) short bf16x8;
typedef __attribute__((ext_vector_type(4))) float f32x4;

__device__ __forceinline__ short f2bf(float x) {
    __hip_bfloat16 h = __float2bfloat16(x);
    return *(short*)&h;
}
__device__ __forceinline__ float silu(float x) {
    return x * (1.0f / (1.0f + __expf(-x)));
}
__device__ __forceinline__ void gl_lds16(const void* src, void* dst) {
    __builtin_amdgcn_global_load_lds(
        (const __attribute__((address_space(1))) void*)src,
        (__attribute__((address_space(3))) void*)dst, 16, 0, 0);
}

// ---------- 1) histogram ----------
__global__ __launch_bounds__(256) void hist_kernel(
    const int* __restrict__ idx, int* __restrict__ counts, int nEdges)
{
    int e = blockIdx.x * 256 + threadIdx.x;
    if (e < nEdges) atomicAdd(&counts[idx[e]], 1);
}

// ---------- 2) scan, pass 1: per-block exclusive scan + block sums ----------
__global__ __launch_bounds__(1024) void scan1_kernel(
    const int* __restrict__ counts, int* __restrict__ starts,
    int* __restrict__ blockSum, int n)
{
    __shared__ int wsum[16];
    int t = threadIdx.x, lane = t & 63, wid = t >> 6;
    int i = blockIdx.x * 1024 + t;
    int v = (i < n) ? counts[i] : 0;
    int incl = v;
    #pragma unroll
    for (int off = 1; off < 64; off <<= 1) {
        int u = __shfl_up(incl, off);
        if (lane >= off) incl += u;
    }
    if (lane == 63) wsum[wid] = incl;
    __syncthreads();
    if (t < 16) {
        int s = wsum[t];
        #pragma unroll
        for (int off = 1; off < 16; off <<= 1) {
            int u = __shfl_up(s, off);
            if (t >= off) s += u;
        }
        wsum[t] = s;
    }
    __syncthreads();
    int woff = (wid == 0) ? 0 : wsum[wid - 1];
    if (i < n) starts[i] = woff + incl - v;     // block-local exclusive
    if (t == 0) blockSum[blockIdx.x] = wsum[15];
}

// ---------- 2b) scan block sums (single small block) ----------
__global__ __launch_bounds__(1024) void scan2_kernel(
    const int* __restrict__ blockSum, int* __restrict__ blockOff,
    int* __restrict__ starts, int nb, int n)
{
    __shared__ int arr[1024];
    int t = threadIdx.x;
    int v = (t < nb) ? blockSum[t] : 0;
    arr[t] = v;
    __syncthreads();
    #pragma unroll
    for (int off = 1; off < 1024; off <<= 1) {
        int x = (t >= off) ? arr[t - off] : 0;
        __syncthreads();
        arr[t] += x;
        __syncthreads();
    }
    if (t < nb) blockOff[t] = arr[t] - v;       // exclusive
    if (t == 0) starts[n] = arr[nb - 1];        // total edges
}

// ---------- 2c) add block offsets, produce starts + cursor ----------
__global__ __launch_bounds__(1024) void scan3_kernel(
    int* __restrict__ starts, int* __restrict__ cursor,
    const int* __restrict__ blockOff, int n)
{
    int i = blockIdx.x * 1024 + threadIdx.x;
    if (i < n) {
        int s = starts[i] + blockOff[blockIdx.x];
        starts[i] = s;
        cursor[i] = s;
    }
}

// ---------- 3) scatter ----------
__global__ __launch_bounds__(256) void scatter_kernel(
    const float* __restrict__ R, const int* __restrict__ idx,
    int* __restrict__ cursor, float4* __restrict__ sorted, int nEdges)
{
    int e = blockIdx.x * 256 + threadIdx.x;
    if (e >= nEdges) return;
    int i = idx[e];
    int j = idx[nEdges + e];
    float rix = R[3*(size_t)i], riy = R[3*(size_t)i+1], riz = R[3*(size_t)i+2];
    float rjx = R[3*(size_t)j], rjy = R[3*(size_t)j+1], rjz = R[3*(size_t)j+2];
    float dx = rjx - rix, dy = rjy - riy, dz = rjz - riz;
    float r = sqrtf(dx*dx + dy*dy + dz*dz);
    float inv = 1.0f / (r + 1e-8f);
    int pos = atomicAdd(&cursor[i], 1);
    sorted[pos] = make_float4(r, dx*inv, dy*inv, dz*inv);
}

// ---------- 4) segmented reduce ----------
__global__ __launch_bounds__(256) void accum_kernel(
    const float4* __restrict__ sorted, const int* __restrict__ starts,
    const float* __restrict__ centers, const float* __restrict__ width,
    float* __restrict__ M0M1, int nAtoms)
{
    int wv = threadIdx.x >> 6, lane = threadIdx.x & 63;
    int atom = blockIdx.x * 4 + wv;
    if (atom >= nAtoms) return;
    int s = starts[atom], e = starts[atom + 1];
    int k = lane >> 2, c = lane & 3;
    float ck = centers[k];
    float w = width[0];
    float inv2w2 = 1.0f / (2.0f * w * w);
    float acc = 0.0f;
    for (int p = s; p < e; ++p) {
        float4 v = sorted[p];
        float diff = v.x - ck;
        float b = __expf(-diff * diff * inv2w2);
        float comp = (c == 0) ? 1.0f : ((c == 1) ? v.y : ((c == 2) ? v.z : v.w));
        acc += b * comp;
    }
    M0M1[(size_t)atom * 64 + lane] = acc;
}

// ---------- W -> bf16 transposed (Wt[n][kpad]) ----------
__global__ __launch_bounds__(256) void convW_kernel(
    const float* __restrict__ W, short* __restrict__ Wt, int K, int Kpad, int N)
{
    int n = blockIdx.x * 256 + threadIdx.x;
    int k = blockIdx.y;
    if (n >= N) return;
    float v = (k < K) ? W[(size_t)k * N + n] : 0.0f;
    Wt[(size_t)n * Kpad + k] = f2bf(v);
}

// ---------- GEMM1 MFMA 128x512: h1 = silu(feat @ W1 + b1), feat on the fly ----------
__global__ __launch_bounds__(512) void gemm1_mfma(
    const float* __restrict__ M0M1, const short* __restrict__ W1t,
    const float* __restrict__ bias, short* __restrict__ C, int M)
{
    __shared__ float MsT[64][128];        // transposed M0M1: [comp][row]  32KB
    __shared__ short Asl[4 * 128 * 8];    // 8KB
    __shared__ short Bsl[4 * 512 * 8];    // 32KB
    int t = threadIdx.x;
    int w = t >> 6, lane = t & 63;
    int wr = w >> 2, wc = w & 3;          // wave grid 2x4: 64 rows x 128 cols each
    int li = lane & 15, lg = lane >> 4;
    int row0 = blockIdx.x * 128;

    // stage M0M1 transposed into LDS (512 threads: each 16 floats of one row)
    {
        int mrow = t >> 2, mo = (t & 3) * 16;
        int gm = row0 + mrow; if (gm > M - 1) gm = M - 1;
        const float4* src = (const float4*)(M0M1 + (size_t)gm * 64 + mo);
        #pragma unroll
        for (int q = 0; q < 4; ++q) {
            float4 v = src[q];
            int c0 = mo + q * 4;
            MsT[c0+0][mrow] = v.x; MsT[c0+1][mrow] = v.y;
            MsT[c0+2][mrow] = v.z; MsT[c0+3][mrow] = v.w;
        }
    }
    f32x4 zz = {0.f, 0.f, 0.f, 0.f};
    f32x4 acc[4][8];
    #pragma unroll
    for (int m = 0; m < 4; ++m)
        #pragma unroll
        for (int n = 0; n < 8; ++n) acc[m][n] = zz;
    __syncthreads();

    for (int k0 = 0; k0 < K1P; k0 += 32) {
        // A tile: compute feat -> bf16 -> Asl[(k8*128+row)*8]; one cell/thread
        {
            int k8 = t >> 7, row = t & 127;
            int kbase = k0 + k8 * 8;
            bf16x8 v;
            if (kbase < 16) {
                #pragma unroll
                for (int j = 0; j < 8; ++j) v[j] = f2bf(MsT[4*(kbase+j)][row]);
            } else if (kbase < 272) {
                int g = kbase - 16, a = g >> 4, b0 = g & 15;
                float ax = MsT[4*a+1][row], ay = MsT[4*a+2][row], az = MsT[4*a+3][row];
                #pragma unroll
                for (int j = 0; j < 8; ++j) {
                    int b = b0 + j;
                    v[j] = f2bf(ax*MsT[4*b+1][row] + ay*MsT[4*b+2][row] + az*MsT[4*b+3][row]);
                }
            } else {
                #pragma unroll
                for (int j = 0; j < 8; ++j) v[j] = 0;
            }
            *(bf16x8*)&Asl[t * 8] = v;
        }
        // B tile: 2048 cells, 4 gl_lds per thread
        #pragma unroll
        for (int p = 0; p < 4; ++p) {
            int cell = (w * 4 + p) * 64 + lane;
            int k8 = cell >> 9, n = cell & 511;
            const short* src = W1t + (size_t)n * K1P + k0 + k8 * 8;
            gl_lds16(src, &Bsl[(w * 4 + p) * 64 * 8]);
        }
        __syncthreads();
        bf16x8 af[4], bfr[8];
        const short* Ab = &Asl[(lg * 128 + wr * 64 + li) * 8];
        const short* Bb = &Bsl[(lg * 512 + wc * 128 + li) * 8];
        #pragma unroll
        for (int m = 0; m < 4; ++m) af[m] = *(const bf16x8*)(Ab + m * 128);
        #pragma unroll
        for (int n = 0; n < 8; ++n) bfr[n] = *(const bf16x8*)(Bb + n * 128);
        #pragma unroll
        for (int m = 0; m < 4; ++m)
            #pragma unroll
            for (int n = 0; n < 8; ++n)
                acc[m][n] = __builtin_amdgcn_mfma_f32_16x16x32_bf16(af[m], bfr[n], acc[m][n], 0, 0, 0);
        __syncthreads();
    }

    float bv[8];
    #pragma unroll
    for (int n = 0; n < 8; ++n) bv[n] = bias[wc * 128 + n * 16 + li];
    #pragma unroll
    for (int m = 0; m < 4; ++m)
        #pragma unroll
        for (int r = 0; r < 4; ++r) {
            int row = row0 + wr * 64 + m * 16 + lg * 4 + r;
            if (row >= M) continue;
            size_t base = (size_t)row * HID + wc * 128 + li;
            #pragma unroll
            for (int n = 0; n < 8; ++n) {
                float cx = acc[m][n][r] + bv[n];
                C[base + n * 16] = f2bf(silu(cx));
            }
        }
}

// ---------- GEMM2 MFMA 128x512 + fused W3/scale/shift/total-energy ----------
__global__ __launch_bounds__(512) void gemm2_mfma(
    const short* __restrict__ A, const short* __restrict__ W2t,
    const float* __restrict__ bias, const float* __restrict__ W3,
    const float* __restrict__ b3, const float* __restrict__ scale,
    const float* __restrict__ shift, const int* __restrict__ Z,
    float* __restrict__ out, int M)
{
    __shared__ short Asl[4 * 128 * 8];    // 8KB
    __shared__ short Bsl[4 * 512 * 8];    // 32KB
    __shared__ float rsum[4][128];
    __shared__ float red[2];
    int t = threadIdx.x;
    int w = t >> 6, lane = t & 63;
    int wr = w >> 2, wc = w & 3;
    int li = lane & 15, lg = lane >> 4;
    int row0 = blockIdx.x * 128;

    f32x4 zz = {0.f, 0.f, 0.f, 0.f};
    f32x4 acc[4][8];
    #pragma unroll
    for (int m = 0; m < 4; ++m)
        #pragma unroll
        for (int n = 0; n < 8; ++n) acc[m][n] = zz;

    for (int k0 = 0; k0 < HID; k0 += 32) {
        // A tile: 512 cells, 1 gl_lds per thread
        {
            int k8 = w >> 1, row = (w & 1) * 64 + lane;
            int gr = row0 + row; if (gr > M - 1) gr = M - 1;
            const short* src = A + (size_t)gr * HID + k0 + k8 * 8;
            gl_lds16(src, &Asl[w * 64 * 8]);
        }
        // B tile: 2048 cells, 4 gl_lds per thread
        #pragma unroll
        for (int p = 0; p < 4; ++p) {
            int cell = (w * 4 + p) * 64 + lane;
            int k8 = cell >> 9, n = cell & 511;
            const short* src = W2t + (size_t)n * HID + k0 + k8 * 8;
            gl_lds16(src, &Bsl[(w * 4 + p) * 64 * 8]);
        }
        __syncthreads();
        bf16x8 af[4], bfr[8];
        const short* Ab = &Asl[(lg * 128 + wr * 64 + li) * 8];
        const short* Bb = &Bsl[(lg * 512 + wc * 128 + li) * 8];
        #pragma unroll
        for (int m = 0; m < 4; ++m) af[m] = *(const bf16x8*)(Ab + m * 128);
        #pragma unroll
        for (int n = 0; n < 8; ++n) bfr[n] = *(const bf16x8*)(Bb + n * 128);
        #pragma unroll
        for (int m = 0; m < 4; ++m)
            #pragma unroll
            for (int n = 0; n < 8; ++n)
                acc[m][n] = __builtin_amdgcn_mfma_f32_16x16x32_bf16(af[m], bfr[n], acc[m][n], 0, 0, 0);
        __syncthreads();
    }

    float bv[8], w3v[8];
    #pragma unroll
    for (int n = 0; n < 8; ++n) {
        int col = wc * 128 + n * 16 + li;
        bv[n] = bias[col];
        w3v[n] = W3[col];
    }
    #pragma unroll
    for (int m = 0; m < 4; ++m)
        #pragma unroll
        for (int r = 0; r < 4; ++r) {
            float s = 0.f;
            #pragma unroll
            for (int n = 0; n < 8; ++n) {
                float cx = acc[m][n][r] + bv[n];
                s += silu(cx) * w3v[n];
            }
            #pragma unroll
            for (int off = 1; off < 16; off <<= 1) s += __shfl_xor(s, off);
            if (li == 0) rsum[wc][wr * 64 + m * 16 + lg * 4 + r] = s;
        }
    __syncthreads();
    float e = 0.f;
    if (t < 128) {
        int row = row0 + t;
        if (row < M) {
            float v = rsum[0][t] + rsum[1][t] + rsum[2][t] + rsum[3][t];
            int z = Z[row];
            e = scale[z] * (v + b3[0]) + shift[z];
        }
        #pragma unroll
        for (int off = 32; off > 0; off >>= 1) e += __shfl_down(e, off);
        if ((t & 63) == 0) red[t >> 6] = e;
    }
    __syncthreads();
    if (t == 0) atomicAdd(out, red[0] + red[1]);
}

extern "C" void kernel_launch(void* const* d_in, const int* in_sizes, int n_in,
                              void* d_out, int out_size, void* d_ws, size_t ws_size,
                              hipStream_t stream)
{
    const float* R       = (const float*)d_in[0];
    const int*   Z       = (const int*)  d_in[1];
    const int*   idx     = (const int*)  d_in[2];
    const float* centers = (const float*)d_in[5];
    const float* width   = (const float*)d_in[6];
    const float* W1      = (const float*)d_in[7];
    const float* b1      = (const float*)d_in[8];
    const float* W2      = (const float*)d_in[9];
    const float* b2      = (const float*)d_in[10];
    const float* W3      = (const float*)d_in[11];
    const float* b3      = (const float*)d_in[12];
    const float* scale   = (const float*)d_in[13];
    const float* shift   = (const float*)d_in[14];

    int nAtoms = in_sizes[0] / 3;
    int nEdges = in_sizes[2] / 2;

    size_t m0m1_b = (size_t)nAtoms * 64 * sizeof(float);   // 25.6 MB
    size_t h1_b   = (size_t)nAtoms * HID * 2;              // 102.4 MB
    size_t w1t_b  = (size_t)HID * K1P * 2;                 // 288 KB
    size_t w2t_b  = (size_t)HID * HID * 2;                 // 512 KB
    if (ws_size < m0m1_b + h1_b + w1t_b + w2t_b) return;   // clean fail, no fault

    char* ws = (char*)d_ws;
    float* M0M1 = (float*)ws;
    char*  regB = ws + m0m1_b;
    short* h1   = (short*)regB;
    short* W1t  = (short*)(ws + m0m1_b + h1_b);
    short* W2t  = W1t + (size_t)HID * K1P;

    // sort scratch aliased into regB (dead before gemm1 writes h1)
    int nb = (nAtoms + 1023) / 1024;
    size_t sorted_b = (size_t)nEdges * sizeof(float4);
    float4* sorted = (float4*)regB;
    int* counts   = (int*)(regB + sorted_b);
    int* starts   = counts + nAtoms;
    int* cursor   = starts + nAtoms + 1;
    int* blockSum = cursor + nAtoms;
    int* blockOff = blockSum + nb;
    if (sorted_b + (size_t)(3 * nAtoms + 1 + 2 * nb) * sizeof(int) > h1_b) return;

    float* out = (float*)d_out;

    hipMemsetAsync(counts, 0, (size_t)nAtoms * sizeof(int), stream);
    hipMemsetAsync(out, 0, sizeof(float), stream);

    convW_kernel<<<dim3(2, K1P), 256, 0, stream>>>(W1, W1t, 272, K1P, HID);
    convW_kernel<<<dim3(2, HID), 256, 0, stream>>>(W2, W2t, HID, HID, HID);

    int eb = (nEdges + 255) / 256;
    hist_kernel <<<eb, 256, 0, stream>>>(idx, counts, nEdges);
    scan1_kernel<<<nb, 1024, 0, stream>>>(counts, starts, blockSum, nAtoms);
    scan2_kernel<<<1, 1024, 0, stream>>>(blockSum, blockOff, starts, nb, nAtoms);
    scan3_kernel<<<nb, 1024, 0, stream>>>(starts, cursor, blockOff, nAtoms);
    scatter_kernel<<<eb, 256, 0, stream>>>(R, idx, cursor, sorted, nEdges);
    accum_kernel<<<(nAtoms + 3) / 4, 256, 0, stream>>>(sorted, starts, centers, width, M0M1, nAtoms);

    int gb = (nAtoms + 127) / 128;
    gemm1_mfma<<<gb, 512, 0, stream>>>(M0M1, W1t, b1, h1, nAtoms);
    gemm2_mfma<<<gb, 512, 0, stream>>>(h1, W2t, b2, W3, b3, scale, shift, Z, out, nAtoms);
}

// Round 6
// 552.816 us; speedup vs baseline: 11.7723x; 1.0773x over previous
//
#include <hip/hip_runtime.h>
#include <hip/hip_bf16.h>
#include <cstdint>

#define HID 512
#define K1P 288   // feat K padded 272 -> 288

typedef __attribute__((ext_vector_type(8))) short bf16x8;
typedef __attribute__((ext_vector_type(4))) float f32x4;

__device__ __forceinline__ short f2bf(float x) {
    __hip_bfloat16 h = __float2bfloat16(x);
    return *(short*)&h;
}
__device__ __forceinline__ float silu(float x) {
    return x * (1.0f / (1.0f + __expf(-x)));
}
__device__ __forceinline__ void gl_lds16(const void* src, void* dst) {
    __builtin_amdgcn_global_load_lds(
        (const __attribute__((address_space(1))) void*)src,
        (__attribute__((address_space(3))) void*)dst, 16, 0, 0);
}

// ---------- 1) histogram ----------
__global__ __launch_bounds__(256) void hist_kernel(
    const int* __restrict__ idx, int* __restrict__ counts, int nEdges)
{
    int e = blockIdx.x * 256 + threadIdx.x;
    if (e < nEdges) atomicAdd(&counts[idx[e]], 1);
}

// ---------- 2) scan, pass 1 ----------
__global__ __launch_bounds__(1024) void scan1_kernel(
    const int* __restrict__ counts, int* __restrict__ starts,
    int* __restrict__ blockSum, int n)
{
    __shared__ int wsum[16];
    int t = threadIdx.x, lane = t & 63, wid = t >> 6;
    int i = blockIdx.x * 1024 + t;
    int v = (i < n) ? counts[i] : 0;
    int incl = v;
    #pragma unroll
    for (int off = 1; off < 64; off <<= 1) {
        int u = __shfl_up(incl, off);
        if (lane >= off) incl += u;
    }
    if (lane == 63) wsum[wid] = incl;
    __syncthreads();
    if (t < 16) {
        int s = wsum[t];
        #pragma unroll
        for (int off = 1; off < 16; off <<= 1) {
            int u = __shfl_up(s, off);
            if (t >= off) s += u;
        }
        wsum[t] = s;
    }
    __syncthreads();
    int woff = (wid == 0) ? 0 : wsum[wid - 1];
    if (i < n) starts[i] = woff + incl - v;
    if (t == 0) blockSum[blockIdx.x] = wsum[15];
}

// ---------- 2b) scan block sums ----------
__global__ __launch_bounds__(1024) void scan2_kernel(
    const int* __restrict__ blockSum, int* __restrict__ blockOff,
    int* __restrict__ starts, int nb, int n)
{
    __shared__ int arr[1024];
    int t = threadIdx.x;
    int v = (t < nb) ? blockSum[t] : 0;
    arr[t] = v;
    __syncthreads();
    #pragma unroll
    for (int off = 1; off < 1024; off <<= 1) {
        int x = (t >= off) ? arr[t - off] : 0;
        __syncthreads();
        arr[t] += x;
        __syncthreads();
    }
    if (t < nb) blockOff[t] = arr[t] - v;
    if (t == 0) starts[n] = arr[nb - 1];
}

// ---------- 2c) add offsets ----------
__global__ __launch_bounds__(1024) void scan3_kernel(
    int* __restrict__ starts, int* __restrict__ cursor,
    const int* __restrict__ blockOff, int n)
{
    int i = blockIdx.x * 1024 + threadIdx.x;
    if (i < n) {
        int s = starts[i] + blockOff[blockIdx.x];
        starts[i] = s;
        cursor[i] = s;
    }
}

// ---------- 3) scatter ----------
__global__ __launch_bounds__(256) void scatter_kernel(
    const float* __restrict__ R, const int* __restrict__ idx,
    int* __restrict__ cursor, float4* __restrict__ sorted, int nEdges)
{
    int e = blockIdx.x * 256 + threadIdx.x;
    if (e >= nEdges) return;
    int i = idx[e];
    int j = idx[nEdges + e];
    float rix = R[3*(size_t)i], riy = R[3*(size_t)i+1], riz = R[3*(size_t)i+2];
    float rjx = R[3*(size_t)j], rjy = R[3*(size_t)j+1], rjz = R[3*(size_t)j+2];
    float dx = rjx - rix, dy = rjy - riy, dz = rjz - riz;
    float r = sqrtf(dx*dx + dy*dy + dz*dz);
    float inv = 1.0f / (r + 1e-8f);
    int pos = atomicAdd(&cursor[i], 1);
    sorted[pos] = make_float4(r, dx*inv, dy*inv, dz*inv);
}

// ---------- 4) segmented reduce ----------
__global__ __launch_bounds__(256) void accum_kernel(
    const float4* __restrict__ sorted, const int* __restrict__ starts,
    const float* __restrict__ centers, const float* __restrict__ width,
    float* __restrict__ M0M1, int nAtoms)
{
    int wv = threadIdx.x >> 6, lane = threadIdx.x & 63;
    int atom = blockIdx.x * 4 + wv;
    if (atom >= nAtoms) return;
    int s = starts[atom], e = starts[atom + 1];
    int k = lane >> 2, c = lane & 3;
    float ck = centers[k];
    float w = width[0];
    float inv2w2 = 1.0f / (2.0f * w * w);
    float acc = 0.0f;
    for (int p = s; p < e; ++p) {
        float4 v = sorted[p];
        float diff = v.x - ck;
        float b = __expf(-diff * diff * inv2w2);
        float comp = (c == 0) ? 1.0f : ((c == 1) ? v.y : ((c == 2) ? v.z : v.w));
        acc += b * comp;
    }
    M0M1[(size_t)atom * 64 + lane] = acc;
}

// ---------- W -> bf16 transposed ----------
__global__ __launch_bounds__(256) void convW_kernel(
    const float* __restrict__ W, short* __restrict__ Wt, int K, int Kpad, int N)
{
    int n = blockIdx.x * 256 + threadIdx.x;
    int k = blockIdx.y;
    if (n >= N) return;
    float v = (k < K) ? W[(size_t)k * N + n] : 0.0f;
    Wt[(size_t)n * Kpad + k] = f2bf(v);
}

// ---------- GEMM1 MFMA 128x256, 2-phase dbuf: h1 = silu(feat @ W1 + b1) ----------
__global__ __launch_bounds__(512) void gemm1_mfma(
    const float* __restrict__ M0M1, const short* __restrict__ W1t,
    const float* __restrict__ bias, short* __restrict__ C, int M)
{
    __shared__ float MsT[64][128];        // 32KB
    __shared__ short Asl[2][4 * 128 * 8]; // 2x8KB
    __shared__ short Bsl[2][4 * 256 * 8]; // 2x16KB
    int t = threadIdx.x;
    int w = t >> 6, lane = t & 63;
    int wr = w >> 2, wc = w & 3;          // 2x4 wave grid: 64 rows x 64 cols each
    int li = lane & 15, lg = lane >> 4;
    int row0 = blockIdx.x * 128;
    int col0 = blockIdx.y * 256;

    // stage M0M1 transposed
    {
        int mrow = t >> 2, mo = (t & 3) * 16;
        int gm = row0 + mrow; if (gm > M - 1) gm = M - 1;
        const float4* src = (const float4*)(M0M1 + (size_t)gm * 64 + mo);
        #pragma unroll
        for (int q = 0; q < 4; ++q) {
            float4 v = src[q];
            int c0 = mo + q * 4;
            MsT[c0+0][mrow] = v.x; MsT[c0+1][mrow] = v.y;
            MsT[c0+2][mrow] = v.z; MsT[c0+3][mrow] = v.w;
        }
    }
    __syncthreads();

    auto stageA = [&](int buf, int k0) {
        int k8 = t >> 7, row = t & 127;
        int kbase = k0 + k8 * 8;
        bf16x8 v;
        if (kbase < 16) {
            #pragma unroll
            for (int j = 0; j < 8; ++j) v[j] = f2bf(MsT[4*(kbase+j)][row]);
        } else if (kbase < 272) {
            int g = kbase - 16, a = g >> 4, b0 = g & 15;
            float ax = MsT[4*a+1][row], ay = MsT[4*a+2][row], az = MsT[4*a+3][row];
            #pragma unroll
            for (int j = 0; j < 8; ++j) {
                int b = b0 + j;
                v[j] = f2bf(ax*MsT[4*b+1][row] + ay*MsT[4*b+2][row] + az*MsT[4*b+3][row]);
            }
        } else {
            #pragma unroll
            for (int j = 0; j < 8; ++j) v[j] = 0;
        }
        *(bf16x8*)&Asl[buf][t * 8] = v;
    };
    auto stageB = [&](int buf, int k0) {
        #pragma unroll
        for (int p = 0; p < 2; ++p) {
            int cell = (w * 2 + p) * 64 + lane;
            int k8 = cell >> 8, n = cell & 255;
            const short* src = W1t + (size_t)(col0 + n) * K1P + k0 + k8 * 8;
            gl_lds16(src, &Bsl[buf][(w * 2 + p) * 64 * 8]);
        }
    };

    f32x4 zz = {0.f, 0.f, 0.f, 0.f};
    f32x4 acc[4][4];
    #pragma unroll
    for (int m = 0; m < 4; ++m)
        #pragma unroll
        for (int n = 0; n < 4; ++n) acc[m][n] = zz;

    stageA(0, 0); stageB(0, 0);
    __syncthreads();

    const int NSTEP = K1P / 32;   // 9
    int cur = 0;
    for (int s = 0; s < NSTEP; ++s) {
        if (s + 1 < NSTEP) { stageB(cur ^ 1, (s + 1) * 32); stageA(cur ^ 1, (s + 1) * 32); }
        bf16x8 af[4], bfr[4];
        const short* Ab = &Asl[cur][(lg * 128 + wr * 64 + li) * 8];
        const short* Bb = &Bsl[cur][(lg * 256 + wc * 64 + li) * 8];
        #pragma unroll
        for (int m = 0; m < 4; ++m) af[m] = *(const bf16x8*)(Ab + m * 128);
        #pragma unroll
        for (int n = 0; n < 4; ++n) bfr[n] = *(const bf16x8*)(Bb + n * 128);
        #pragma unroll
        for (int m = 0; m < 4; ++m)
            #pragma unroll
            for (int n = 0; n < 4; ++n)
                acc[m][n] = __builtin_amdgcn_mfma_f32_16x16x32_bf16(af[m], bfr[n], acc[m][n], 0, 0, 0);
        __syncthreads();
        cur ^= 1;
    }

    float bv[4];
    #pragma unroll
    for (int n = 0; n < 4; ++n) bv[n] = bias[col0 + wc * 64 + n * 16 + li];
    #pragma unroll
    for (int m = 0; m < 4; ++m)
        #pragma unroll
        for (int r = 0; r < 4; ++r) {
            int row = row0 + wr * 64 + m * 16 + lg * 4 + r;
            if (row >= M) continue;
            size_t base = (size_t)row * HID + col0 + wc * 64 + li;
            #pragma unroll
            for (int n = 0; n < 4; ++n) {
                float cx = acc[m][n][r] + bv[n];
                C[base + n * 16] = f2bf(silu(cx));
            }
        }
}

// ---------- GEMM2 MFMA 128x256, 2-phase dbuf + fused energy epilogue ----------
__global__ __launch_bounds__(512) void gemm2_mfma(
    const short* __restrict__ A, const short* __restrict__ W2t,
    const float* __restrict__ bias, const float* __restrict__ W3,
    const float* __restrict__ b3, const float* __restrict__ scale,
    const float* __restrict__ shift, const int* __restrict__ Z,
    float* __restrict__ out, int M)
{
    __shared__ short Asl[2][4 * 128 * 8]; // 2x8KB
    __shared__ short Bsl[2][4 * 256 * 8]; // 2x16KB
    __shared__ float rsum[4][128];
    __shared__ float red[2];
    int t = threadIdx.x;
    int w = t >> 6, lane = t & 63;
    int wr = w >> 2, wc = w & 3;
    int li = lane & 15, lg = lane >> 4;
    int row0 = blockIdx.x * 128;
    int col0 = blockIdx.y * 256;

    auto stageA = [&](int buf, int k0) {
        int k8 = w >> 1, row = (w & 1) * 64 + lane;
        int gr = row0 + row; if (gr > M - 1) gr = M - 1;
        const short* src = A + (size_t)gr * HID + k0 + k8 * 8;
        gl_lds16(src, &Asl[buf][w * 64 * 8]);
    };
    auto stageB = [&](int buf, int k0) {
        #pragma unroll
        for (int p = 0; p < 2; ++p) {
            int cell = (w * 2 + p) * 64 + lane;
            int k8 = cell >> 8, n = cell & 255;
            const short* src = W2t + (size_t)(col0 + n) * HID + k0 + k8 * 8;
            gl_lds16(src, &Bsl[buf][(w * 2 + p) * 64 * 8]);
        }
    };

    f32x4 zz = {0.f, 0.f, 0.f, 0.f};
    f32x4 acc[4][4];
    #pragma unroll
    for (int m = 0; m < 4; ++m)
        #pragma unroll
        for (int n = 0; n < 4; ++n) acc[m][n] = zz;

    stageA(0, 0); stageB(0, 0);
    __syncthreads();

    const int NSTEP = HID / 32;   // 16
    int cur = 0;
    for (int s = 0; s < NSTEP; ++s) {
        if (s + 1 < NSTEP) { stageA(cur ^ 1, (s + 1) * 32); stageB(cur ^ 1, (s + 1) * 32); }
        bf16x8 af[4], bfr[4];
        const short* Ab = &Asl[cur][(lg * 128 + wr * 64 + li) * 8];
        const short* Bb = &Bsl[cur][(lg * 256 + wc * 64 + li) * 8];
        #pragma unroll
        for (int m = 0; m < 4; ++m) af[m] = *(const bf16x8*)(Ab + m * 128);
        #pragma unroll
        for (int n = 0; n < 4; ++n) bfr[n] = *(const bf16x8*)(Bb + n * 128);
        #pragma unroll
        for (int m = 0; m < 4; ++m)
            #pragma unroll
            for (int n = 0; n < 4; ++n)
                acc[m][n] = __builtin_amdgcn_mfma_f32_16x16x32_bf16(af[m], bfr[n], acc[m][n], 0, 0, 0);
        __syncthreads();
        cur ^= 1;
    }

    float bv[4], w3v[4];
    #pragma unroll
    for (int n = 0; n < 4; ++n) {
        int col = col0 + wc * 64 + n * 16 + li;
        bv[n] = bias[col];
        w3v[n] = W3[col];
    }
    #pragma unroll
    for (int m = 0; m < 4; ++m)
        #pragma unroll
        for (int r = 0; r < 4; ++r) {
            float s = 0.f;
            #pragma unroll
            for (int n = 0; n < 4; ++n) {
                float cx = acc[m][n][r] + bv[n];
                s += silu(cx) * w3v[n];
            }
            #pragma unroll
            for (int off = 1; off < 16; off <<= 1) s += __shfl_xor(s, off);
            if (li == 0) rsum[wc][wr * 64 + m * 16 + lg * 4 + r] = s;
        }
    __syncthreads();
    float e = 0.f;
    if (t < 128) {
        int row = row0 + t;
        if (row < M) {
            float v = rsum[0][t] + rsum[1][t] + rsum[2][t] + rsum[3][t];
            int z = Z[row];
            e = scale[z] * v;
            if (blockIdx.y == 0) e += scale[z] * b3[0] + shift[z];
        }
        #pragma unroll
        for (int off = 32; off > 0; off >>= 1) e += __shfl_down(e, off);
        if ((t & 63) == 0) red[t >> 6] = e;
    }
    __syncthreads();
    if (t == 0) atomicAdd(out, red[0] + red[1]);
}

extern "C" void kernel_launch(void* const* d_in, const int* in_sizes, int n_in,
                              void* d_out, int out_size, void* d_ws, size_t ws_size,
                              hipStream_t stream)
{
    const float* R       = (const float*)d_in[0];
    const int*   Z       = (const int*)  d_in[1];
    const int*   idx     = (const int*)  d_in[2];
    const float* centers = (const float*)d_in[5];
    const float* width   = (const float*)d_in[6];
    const float* W1      = (const float*)d_in[7];
    const float* b1      = (const float*)d_in[8];
    const float* W2      = (const float*)d_in[9];
    const float* b2      = (const float*)d_in[10];
    const float* W3      = (const float*)d_in[11];
    const float* b3      = (const float*)d_in[12];
    const float* scale   = (const float*)d_in[13];
    const float* shift   = (const float*)d_in[14];

    int nAtoms = in_sizes[0] / 3;
    int nEdges = in_sizes[2] / 2;

    size_t m0m1_b = (size_t)nAtoms * 64 * sizeof(float);   // 25.6 MB
    size_t h1_b   = (size_t)nAtoms * HID * 2;              // 102.4 MB
    size_t w1t_b  = (size_t)HID * K1P * 2;                 // 288 KB
    size_t w2t_b  = (size_t)HID * HID * 2;                 // 512 KB
    if (ws_size < m0m1_b + h1_b + w1t_b + w2t_b) return;

    char* ws = (char*)d_ws;
    float* M0M1 = (float*)ws;
    char*  regB = ws + m0m1_b;
    short* h1   = (short*)regB;
    short* W1t  = (short*)(ws + m0m1_b + h1_b);
    short* W2t  = W1t + (size_t)HID * K1P;

    int nb = (nAtoms + 1023) / 1024;
    size_t sorted_b = (size_t)nEdges * sizeof(float4);
    float4* sorted = (float4*)regB;
    int* counts   = (int*)(regB + sorted_b);
    int* starts   = counts + nAtoms;
    int* cursor   = starts + nAtoms + 1;
    int* blockSum = cursor + nAtoms;
    int* blockOff = blockSum + nb;
    if (sorted_b + (size_t)(3 * nAtoms + 1 + 2 * nb) * sizeof(int) > h1_b) return;

    float* out = (float*)d_out;

    hipMemsetAsync(counts, 0, (size_t)nAtoms * sizeof(int), stream);
    hipMemsetAsync(out, 0, sizeof(float), stream);

    convW_kernel<<<dim3(2, K1P), 256, 0, stream>>>(W1, W1t, 272, K1P, HID);
    convW_kernel<<<dim3(2, HID), 256, 0, stream>>>(W2, W2t, HID, HID, HID);

    int eb = (nEdges + 255) / 256;
    hist_kernel <<<eb, 256, 0, stream>>>(idx, counts, nEdges);
    scan1_kernel<<<nb, 1024, 0, stream>>>(counts, starts, blockSum, nAtoms);
    scan2_kernel<<<1, 1024, 0, stream>>>(blockSum, blockOff, starts, nb, nAtoms);
    scan3_kernel<<<nb, 1024, 0, stream>>>(starts, cursor, blockOff, nAtoms);
    scatter_kernel<<<eb, 256, 0, stream>>>(R, idx, cursor, sorted, nEdges);
    accum_kernel<<<(nAtoms + 3) / 4, 256, 0, stream>>>(sorted, starts, centers, width, M0M1, nAtoms);

    int gb = (nAtoms + 127) / 128;
    dim3 g(gb, 2);
    gemm1_mfma<<<g, 512, 0, stream>>>(M0M1, W1t, b1, h1, nAtoms);
    gemm2_mfma<<<g, 512, 0, stream>>>(h1, W2t, b2, W3, b3, scale, shift, Z, out, nAtoms);
}